// Round 23
// baseline (17.731 us; speedup 1.0000x reference)
//
#include <hip/hip_runtime.h>
#include <stdint.h>

#define B_SZ    8
#define N_PTS   4096
#define C_IN    64
#define C_OUT   64
#define KNN     16
#define ROWS    (B_SZ * N_PTS)      // 32768

typedef __attribute__((ext_vector_type(8))) short v8s;   // 8 bf16 (4 VGPR)
typedef __attribute__((ext_vector_type(4))) float v4f;   // MFMA acc

__device__ inline unsigned short f2bf(float f) {         // RNE f32->bf16
    unsigned int u = __float_as_uint(f);
    return (unsigned short)((u + 0x7FFFu + ((u >> 16) & 1u)) >> 16);
}

__device__ inline v8s pack8(float4 q0, float4 q1) {
    v8s a;
    a[0] = (short)f2bf(q0.x); a[1] = (short)f2bf(q0.y);
    a[2] = (short)f2bf(q0.z); a[3] = (short)f2bf(q0.w);
    a[4] = (short)f2bf(q1.x); a[5] = (short)f2bf(q1.y);
    a[6] = (short)f2bf(q1.z); a[7] = (short)f2bf(q1.w);
    return a;
}

#define PITCH 68    // 68 % 32 == 4: col-strided frag reads are 2-way (free)

// ---------------------------------------------------------------------------
// Kernel A: BOTH projections in one pass.
//   cbuf[r][o] = x[r]·(W1-W2)[o] + bias[o]   (fp32, global)
//   nbuf[r][o] = x[r]·W2[o]                  (bf16, global)
// 32 rows/block, grid 1024 (4 blocks/CU). Wave = (row half) x (col half);
// same afrag feeds both accumulator sets (8 MFMAs). Both weight sets staged
// to LDS in one coalesced pass (w1,w2 loaded once; wld=w1-w2, wl2=w2).
// ---------------------------------------------------------------------------
__global__ __launch_bounds__(256, 4) void proj_both(
    const float* __restrict__ x,
    const float* __restrict__ w,
    const float* __restrict__ bias,
    float* __restrict__ cbuf,
    unsigned short* __restrict__ nbuf)
{
    __shared__ float wld[C_OUT][PITCH];     // (W1-W2)[col][k]
    __shared__ float wl2[C_OUT][PITCH];     // W2[col][k]      (35 KB total)

    const int t     = threadIdx.x;
    const int lane  = t & 63;
    const int wv    = t >> 6;
    const int rq    = wv & 1;                            // row half
    const int ch    = wv >> 1;                           // col half
    const int batch = blockIdx.x & 7;                    // XCD-affine
    const int chunk = blockIdx.x >> 3;                   // 0..127
    const int r0    = batch * N_PTS + chunk * 32 + rq * 16;

    const int fc   = lane & 15;
    const int koff = 8 * (lane >> 4);

    // afrag: direct from x (issues before the barrier)
    const int arow = r0 + fc;
    v8s afrag[2];
#pragma unroll
    for (int ks = 0; ks < 2; ++ks) {
        const float* xp = x + (size_t)arow * C_IN + ks * 32 + koff;
        afrag[ks] = pack8(*(const float4*)xp, *(const float4*)(xp + 4));
    }

    // stage both weight views (coalesced; w1/w2 loaded exactly once)
#pragma unroll
    for (int i = 0; i < 4; ++i) {
        const int idx = i * 256 + t;        // 0..1023
        const int col = idx >> 4;
        const int q   = (idx & 15) * 4;
        const float4 w1 = *(const float4*)(w + col * 128 + q);
        const float4 w2 = *(const float4*)(w + col * 128 + 64 + q);
        *(float4*)&wld[col][q] =
            make_float4(w1.x - w2.x, w1.y - w2.y, w1.z - w2.z, w1.w - w2.w);
        *(float4*)&wl2[col][q] = w2;
    }
    __syncthreads();

    v8s bC[2][2], bN[2][2];
#pragma unroll
    for (int ct = 0; ct < 2; ++ct) {
        const int col = ch * 32 + ct * 16 + fc;
#pragma unroll
        for (int ks = 0; ks < 2; ++ks) {
            const float* pc = &wld[col][ks * 32 + koff];
            const float* pn = &wl2[col][ks * 32 + koff];
            bC[ct][ks] = pack8(*(const float4*)pc, *(const float4*)(pc + 4));
            bN[ct][ks] = pack8(*(const float4*)pn, *(const float4*)(pn + 4));
        }
    }

    v4f accC[2], accN[2];
#pragma unroll
    for (int ct = 0; ct < 2; ++ct) {
        const float bv = bias[ch * 32 + ct * 16 + fc];
        accC[ct] = (v4f){bv, bv, bv, bv};
        accN[ct] = (v4f){0.f, 0.f, 0.f, 0.f};
    }
#pragma unroll
    for (int ks = 0; ks < 2; ++ks)
#pragma unroll
        for (int ct = 0; ct < 2; ++ct) {
            accC[ct] = __builtin_amdgcn_mfma_f32_16x16x32_bf16(
                afrag[ks], bC[ct][ks], accC[ct], 0, 0, 0);
            accN[ct] = __builtin_amdgcn_mfma_f32_16x16x32_bf16(
                afrag[ks], bN[ct][ks], accN[ct], 0, 0, 0);
        }

    const int crow0 = r0 + (lane >> 4) * 4;
#pragma unroll
    for (int ct = 0; ct < 2; ++ct)
#pragma unroll
        for (int reg = 0; reg < 4; ++reg) {
            const size_t off = (size_t)(crow0 + reg) * C_OUT + ch * 32 + ct * 16 + fc;
            cbuf[off] = accC[ct][reg];
            nbuf[off] = f2bf(accN[ct][reg]);
        }
}

// ---------------------------------------------------------------------------
// Kernel B: PURE gather + max + relu + transposed store. No w, no x, no MFMA,
// ONE barrier.  Lane owns (row rbl, channels o8..o8+7).
//   out[b][o][n] = relu( cbuf[n][o] + max_k nbuf[idx[n,k]][o] )
// ---------------------------------------------------------------------------
__global__ __launch_bounds__(256, 4) void gather_only(
    const float* __restrict__ cbuf,
    const unsigned short* __restrict__ nbuf,
    const int* __restrict__ eidx,
    float* __restrict__ out)
{
    __shared__ float sm[32][PITCH];         // 8.5 KB result tile

    const int t    = threadIdx.x;
    const int lane = t & 63;
    const int wv   = t >> 6;                // wave 0..3
    const int b    = blockIdx.x & 7;        // batch == XCD
    const int tn   = blockIdx.x >> 3;       // 0..127
    const int n0   = tn * 32;
    const int r0g  = b * N_PTS + n0;

    const int sub = lane >> 3;              // 0..7
    const int o8  = (lane & 7) * 8;         // 8 channels per lane
    const int rbl = wv * 8 + sub;           // local row

    // ---- indices: per-lane direct (8 lanes share each 64B line) ----
    int pidx[KNN];
    {
        const int* ep = eidx + (size_t)(r0g + rbl) * KNN;
        const int4 i0 = *(const int4*)ep;
        const int4 i1 = *(const int4*)(ep + 4);
        const int4 i2 = *(const int4*)(ep + 8);
        const int4 i3 = *(const int4*)(ep + 12);
        pidx[0]=i0.x&(N_PTS-1); pidx[1]=i0.y&(N_PTS-1); pidx[2]=i0.z&(N_PTS-1); pidx[3]=i0.w&(N_PTS-1);
        pidx[4]=i1.x&(N_PTS-1); pidx[5]=i1.y&(N_PTS-1); pidx[6]=i1.z&(N_PTS-1); pidx[7]=i1.w&(N_PTS-1);
        pidx[8]=i2.x&(N_PTS-1); pidx[9]=i2.y&(N_PTS-1); pidx[10]=i2.z&(N_PTS-1); pidx[11]=i2.w&(N_PTS-1);
        pidx[12]=i3.x&(N_PTS-1); pidx[13]=i3.y&(N_PTS-1); pidx[14]=i3.z&(N_PTS-1); pidx[15]=i3.w&(N_PTS-1);
    }

    // ---- central values (coalesced 32B/lane) ----
    const float* cp = cbuf + (size_t)(r0g + rbl) * C_OUT + o8;
    const float4 cva = *(const float4*)cp;
    const float4 cvb = *(const float4*)(cp + 4);

    // ---- gather + max (16 uint4 loads, bf16 rows, L2-local) ----
    const unsigned short* nb = nbuf + (size_t)b * N_PTS * C_OUT;
    float m0 = -1e30f, m1 = -1e30f, m2 = -1e30f, m3 = -1e30f;
    float m4 = -1e30f, m5 = -1e30f, m6 = -1e30f, m7 = -1e30f;
#pragma unroll
    for (int k = 0; k < KNN; ++k) {
        const uint4 v = *(const uint4*)(nb + (size_t)pidx[k] * C_OUT + o8);
        m0 = fmaxf(m0, __uint_as_float(v.x << 16));
        m1 = fmaxf(m1, __uint_as_float(v.x & 0xffff0000u));
        m2 = fmaxf(m2, __uint_as_float(v.y << 16));
        m3 = fmaxf(m3, __uint_as_float(v.y & 0xffff0000u));
        m4 = fmaxf(m4, __uint_as_float(v.z << 16));
        m5 = fmaxf(m5, __uint_as_float(v.z & 0xffff0000u));
        m6 = fmaxf(m6, __uint_as_float(v.w << 16));
        m7 = fmaxf(m7, __uint_as_float(v.w & 0xffff0000u));
    }

    sm[rbl][o8 + 0] = fmaxf(cva.x + m0, 0.f);   // relu(max)==max(relu)
    sm[rbl][o8 + 1] = fmaxf(cva.y + m1, 0.f);
    sm[rbl][o8 + 2] = fmaxf(cva.z + m2, 0.f);
    sm[rbl][o8 + 3] = fmaxf(cva.w + m3, 0.f);
    sm[rbl][o8 + 4] = fmaxf(cvb.x + m4, 0.f);
    sm[rbl][o8 + 5] = fmaxf(cvb.y + m5, 0.f);
    sm[rbl][o8 + 6] = fmaxf(cvb.z + m6, 0.f);
    sm[rbl][o8 + 7] = fmaxf(cvb.w + m7, 0.f);

    __syncthreads();

    // ---- transposed coalesced store ----
    float* ob = out + (size_t)b * C_OUT * N_PTS + n0;
    const int nn = lane & 31;
    const int oh = lane >> 5;
#pragma unroll
    for (int j = 0; j < 8; ++j) {
        const int o = wv * 16 + j * 2 + oh;
        ob[(size_t)o * N_PTS + nn] = sm[nn][o];   // 2x128B segments
    }
}

// ---------------------------------------------------------------------------
extern "C" void kernel_launch(void* const* d_in, const int* in_sizes, int n_in,
                              void* d_out, int out_size, void* d_ws, size_t ws_size,
                              hipStream_t stream)
{
    const float* x    = (const float*)d_in[0];
    const int*   eidx = (const int*)d_in[1];    // int64 in ref -> int32 here
    const float* w    = (const float*)d_in[2];  // (64, 128)
    const float* bias = (const float*)d_in[3];  // (64,)
    float*       out  = (float*)d_out;          // (8, 64, 64, 64) f32

    unsigned short* nbuf = (unsigned short*)d_ws;                   // 4 MiB
    float*          cbuf = (float*)(nbuf + (size_t)ROWS * C_OUT);   // 8 MiB

    proj_both<<<ROWS / 32, 256, 0, stream>>>(x, w, bias, cbuf, nbuf);
    gather_only<<<ROWS / 32, 256, 0, stream>>>(cbuf, nbuf, eidx, out);
}